// Round 11
// baseline (526.165 us; speedup 1.0000x reference)
//
#include <hip/hip_runtime.h>
#include <hip/hip_bf16.h>

// Problem constants
#define BB 64     // batch
#define NT 128    // text tokens
#define NV 256    // visual tokens
#define DD 512    // feature dim (bytes per row in fp8)
#define BKB 128   // K-chunk in bytes: one 16x16x128 f8f6f4 k-step
#define EPSF 1e-7f

typedef __attribute__((ext_vector_type(8))) int i32x8;
typedef __attribute__((ext_vector_type(4))) int i32x4;
typedef __attribute__((ext_vector_type(4))) float f32x4;

__device__ __forceinline__ void glds16(const uchar* g, uchar* l) {
    __builtin_amdgcn_global_load_lds(
        (const __attribute__((address_space(1))) unsigned int*)g,
        (__attribute__((address_space(3))) unsigned int*)l, 16, 0, 0);
}

// ---------------------------------------------------------------------------
// Kernel 1: L2-normalize rows, write fp8 e4m3 (OCP). Wave per row.
// ---------------------------------------------------------------------------
__global__ __launch_bounds__(256) void k_normalize(
    const float* __restrict__ tf, const float* __restrict__ vf,
    uchar* __restrict__ tn, uchar* __restrict__ vn,
    float* __restrict__ reg_sum) {
    if (blockIdx.x == 0 && threadIdx.x == 0) *reg_sum = 0.0f;
    const int w = threadIdx.x >> 6, l = threadIdx.x & 63;
    const int row = blockIdx.x * 4 + w;
    const float* src;
    uchar* dst;
    if (row < BB * NT) {
        src = tf + (size_t)row * DD;
        dst = tn + (size_t)row * DD;
    } else {
        int r = row - BB * NT;
        src = vf + (size_t)r * DD;
        dst = vn + (size_t)r * DD;
    }
    float4 x0 = ((const float4*)src)[l * 2];
    float4 x1 = ((const float4*)src)[l * 2 + 1];
    float ss = x0.x * x0.x + x0.y * x0.y + x0.z * x0.z + x0.w * x0.w
             + x1.x * x1.x + x1.y * x1.y + x1.z * x1.z + x1.w * x1.w;
    #pragma unroll
    for (int off = 32; off; off >>= 1) ss += __shfl_xor(ss, off, 64);
    float scale = 1.0f / fmaxf(sqrtf(ss), 1e-12f);
    int p0 = __builtin_amdgcn_cvt_pk_fp8_f32(x0.x * scale, x0.y * scale, 0, 0);
    p0 = __builtin_amdgcn_cvt_pk_fp8_f32(x0.z * scale, x0.w * scale, p0, 1);
    int p1 = __builtin_amdgcn_cvt_pk_fp8_f32(x1.x * scale, x1.y * scale, 0, 0);
    p1 = __builtin_amdgcn_cvt_pk_fp8_f32(x1.z * scale, x1.w * scale, p1, 1);
    ((uint2*)dst)[l] = make_uint2((unsigned)p0, (unsigned)p1);
}

// ---------------------------------------------------------------------------
// Kernel 2: ROUND-11 -- R8's EXACT per-wave structure (512 thr, 8 waves 2x4,
// acc[4][4], VGPR=128, the only spill-free shape) but each block handles
// FOUR j values: (i, j0..j0+3). T (64 KB = all 4 K-chunks) is staged into
// LDS ONCE; the 16-step loop stages only V chunks (4 loads/step, R8's
// counted vmcnt(4) FIFO, never 0 mid-loop). The per-j flush (row-max +
// clip) uses raw lgkmcnt(0)+s_barrier -- NOT __syncthreads, whose implicit
// vmcnt(0) would drain the next j's V prefetch -- so epilogue VALU overlaps
// the next j's staging. Amortizes 12/16 prologues per CU and 3/4 of T
// staging. LDS 64(T) + 64(V dbuf) + ~2.1 KB = ~133 KB, 1 block/CU.
// ---------------------------------------------------------------------------
__global__ __launch_bounds__(512, 2) void k_gemm(
    const uchar* __restrict__ tn, const uchar* __restrict__ vn,
    const int* __restrict__ mask,
    float* __restrict__ clip_sims, float* __restrict__ reg_sum) {
    __shared__ uchar sT[4][NT * BKB];  // 4 x 16 KB: ALL K-chunks of T
    __shared__ uchar sV0[NV * BKB];    // 32 KB
    __shared__ uchar sV1[NV * BKB];    // 32 KB
    __shared__ float maxbuf[NT][4];    // row-max partials per wave col-group
    __shared__ float redw[8];
    __shared__ float c0[2], c1[2];

    const int i = blockIdx.x;
    const int j0 = blockIdx.y * 4;
    const int tid = threadIdx.x;
    const int l = tid & 63, w = tid >> 6;
    const int wr = w >> 2, wc = w & 3;      // wave row-group (0..1), col-group (0..3)
    const int m15 = l & 15, q = l >> 4;

    const uchar* tbase = tn + (size_t)i * NT * DD;

    // Staging: 16B unit f -> row r = f>>3, phys granule p = f&7 holds
    // logical granule g = (p - r) & 7.  src = r*DD + kk + g*16.
    int t_off[2], v_off[4];
    #pragma unroll
    for (int s = 0; s < 2; ++s) {
        int f = s * 512 + tid;
        int r = f >> 3, p = f & 7, g = (p - r) & 7;
        t_off[s] = r * DD + g * 16;
    }
    #pragma unroll
    for (int s = 0; s < 4; ++s) {
        int f = s * 512 + tid;
        int r = f >> 3, p = f & 7, g = (p - r) & 7;
        v_off[s] = r * DD + g * 16;
    }

    // Fragment read addresses (rotation-mirrored, verified):
    int a_b0[4], a_b1[4], b_b0[4], b_b1[4];
    #pragma unroll
    for (int rt = 0; rt < 4; ++rt) {
        int row = wr * 64 + rt * 16 + m15;
        a_b0[rt] = row * BKB + (((2 * q + row) & 7) * 16);
        a_b1[rt] = row * BKB + (((2 * q + 1 + row) & 7) * 16);
    }
    #pragma unroll
    for (int ct = 0; ct < 4; ++ct) {
        int row = wc * 64 + ct * 16 + m15;
        b_b0[ct] = row * BKB + (((2 * q + row) & 7) * 16);
        b_b1[ct] = row * BKB + (((2 * q + 1 + row) & 7) * 16);
    }

    f32x4 acc[4][4];
    float rp = 0.0f;

    auto stageV = [&](uchar* dV, const uchar* vb, int kk) {
        #pragma unroll
        for (int s = 0; s < 4; ++s)
            glds16(vb + v_off[s] + kk, dV + (s * 512 + tid) * 16);
    };
    auto compute = [&](const uchar* bT, const uchar* bV) {
        i32x8 bf[4];
        #pragma unroll
        for (int ct = 0; ct < 4; ++ct) {
            i32x4 lo = *(const i32x4*)(bV + b_b0[ct]);
            i32x4 hi = *(const i32x4*)(bV + b_b1[ct]);
            bf[ct] = (i32x8){lo.x, lo.y, lo.z, lo.w, hi.x, hi.y, hi.z, hi.w};
        }
        #pragma unroll
        for (int rt = 0; rt < 4; ++rt) {
            i32x4 lo = *(const i32x4*)(bT + a_b0[rt]);
            i32x4 hi = *(const i32x4*)(bT + a_b1[rt]);
            i32x8 a = (i32x8){lo.x, lo.y, lo.z, lo.w, hi.x, hi.y, hi.z, hi.w};
            #pragma unroll
            for (int ct = 0; ct < 4; ++ct)
                acc[rt][ct] = __builtin_amdgcn_mfma_scale_f32_16x16x128_f8f6f4(
                    a, bf[ct], acc[rt][ct],
                    0 /*A fmt=fp8*/, 0 /*B fmt=fp8*/,
                    0, 127 /*scaleA=1.0*/, 0, 127 /*scaleB=1.0*/);
        }
    };

    // Prologue: ALL of T (8 loads), then V chunks m=0,1 (8 loads). 16 out.
    #pragma unroll
    for (int c = 0; c < 4; ++c)
        #pragma unroll
        for (int s = 0; s < 2; ++s)
            glds16(tbase + t_off[s] + c * BKB, sT[c] + (s * 512 + tid) * 16);
    {
        const uchar* vb = vn + (size_t)j0 * NV * DD;
        stageV(sV0, vb, 0);
        stageV(sV1, vb, BKB);
    }

    // 16 chunk-steps: m = jj*4 + k. Per-wave FIFO: at step m the outstanding
    // loads are {V(m):4, V(m+1):4} (plus T at m=0) -> vmcnt(4) retires
    // exactly what step m needs; vmcnt(0) only at the last step.
    #pragma unroll
    for (int jj = 0; jj < 4; ++jj) {
        #pragma unroll
        for (int rt = 0; rt < 4; ++rt)
            #pragma unroll
            for (int ct = 0; ct < 4; ++ct) acc[rt][ct] = (f32x4){0.f, 0.f, 0.f, 0.f};

        #pragma unroll
        for (int k = 0; k < 4; ++k) {
            const int m = jj * 4 + k;
            if (m < 15) { asm volatile("s_waitcnt vmcnt(4)" ::: "memory"); }
            else        { asm volatile("s_waitcnt vmcnt(0)" ::: "memory"); }
            __builtin_amdgcn_s_barrier();
            asm volatile("" ::: "memory");
            compute(sT[k], (m & 1) ? sV1 : sV0);
            asm volatile("" ::: "memory");
            __builtin_amdgcn_s_barrier();
            const int mn = m + 2;
            if (mn < 16) {
                const uchar* vb = vn + (size_t)(j0 + (mn >> 2)) * NV * DD;
                stageV((mn & 1) ? sV1 : sV0, vb, (mn & 3) * BKB);
            }
        }

        // --- flush jj (raw barriers: must NOT drain vmcnt -- the next j's
        // V prefetch is in flight and covers this VALU work) --------------
        #pragma unroll
        for (int rt = 0; rt < 4; ++rt)
            #pragma unroll
            for (int ct = 0; ct < 4; ++ct)
                #pragma unroll
                for (int r = 0; r < 4; ++r) {
                    float m = fminf(acc[rt][ct][r], 0.0f);
                    rp = fmaf(m, m, rp);
                }
        #pragma unroll
        for (int rt = 0; rt < 4; ++rt)
            #pragma unroll
            for (int r = 0; r < 4; ++r) {
                float m = acc[rt][0][r];
                #pragma unroll
                for (int ct = 1; ct < 4; ++ct) m = fmaxf(m, acc[rt][ct][r]);
                #pragma unroll
                for (int msk = 1; msk < 16; msk <<= 1)
                    m = fmaxf(m, __shfl_xor(m, msk, 64));
                if (m15 == 0)
                    maxbuf[wr * 64 + rt * 16 + q * 4 + r][wc] = m;
            }
        asm volatile("s_waitcnt lgkmcnt(0)" ::: "memory");
        __builtin_amdgcn_s_barrier();      // maxbuf visible to all waves
        asm volatile("" ::: "memory");
        if (tid < NT) {
            float rm = fmaxf(fmaxf(maxbuf[tid][0], maxbuf[tid][1]),
                             fmaxf(maxbuf[tid][2], maxbuf[tid][3]));
            float mf = (float)mask[i * NT + tid];
            float v = rm * mf;
            #pragma unroll
            for (int off = 32; off; off >>= 1) {
                v += __shfl_down(v, off, 64);
                mf += __shfl_down(mf, off, 64);
            }
            if (l == 0) { c0[w] = v; c1[w] = mf; }
        }
        asm volatile("s_waitcnt lgkmcnt(0)" ::: "memory");
        __builtin_amdgcn_s_barrier();      // c0/c1 visible; maxbuf reusable
        asm volatile("" ::: "memory");
        if (tid == 0)
            clip_sims[i * BB + j0 + jj] =
                (c0[0] + c0[1]) / fmaxf(c1[0] + c1[1], EPSF);
    }

    // Final: block-wide reg-loss reduce + one atomic.
    #pragma unroll
    for (int off = 32; off; off >>= 1) rp += __shfl_down(rp, off, 64);
    if (l == 0) redw[w] = rp;
    __syncthreads();
    if (tid == 0) {
        float s = 0.0f;
        #pragma unroll
        for (int x = 0; x < 8; ++x) s += redw[x];
        atomicAdd(reg_sum, s);
    }
}

// ---------------------------------------------------------------------------
// Kernel 3: final scalar loss. Single block, 256 threads.
// ---------------------------------------------------------------------------
__global__ __launch_bounds__(256) void k_loss(
    const float* __restrict__ clip_sims, const float* __restrict__ reg_sum,
    float* __restrict__ out) {
    __shared__ float sc[BB][BB + 1];
    __shared__ float lrow[BB], lcol[BB];
    int tid = threadIdx.x;
    for (int idx = tid; idx < BB * BB; idx += 256)
        sc[idx / BB][idx % BB] = clip_sims[idx];
    __syncthreads();
    if (tid < BB) {
        int i = tid;
        float m = sc[i][0];
        #pragma unroll
        for (int j = 1; j < BB; ++j) m = fmaxf(m, sc[i][j]);
        float s = 0.0f;
        #pragma unroll
        for (int j = 0; j < BB; ++j) s += expf(sc[i][j] - m);
        lrow[i] = m + logf(s) - sc[i][i];
    } else if (tid < 2 * BB) {
        int i = tid - BB;
        float m = sc[0][i];
        #pragma unroll
        for (int j = 1; j < BB; ++j) m = fmaxf(m, sc[j][i]);
        float s = 0.0f;
        #pragma unroll
        for (int j = 0; j < BB; ++j) s += expf(sc[j][i] - m);
        lcol[i] = m + logf(s) - sc[i][i];
    }
    __syncthreads();
    if (tid == 0) {
        float tot = 0.0f;
        for (int i = 0; i < BB; ++i) tot += lrow[i] + lcol[i];
        float contrastive = tot / (2.0f * BB);
        double denom = (double)BB * BB * NT * NV;  // 134217728
        float reg = 0.15f * (float)((double)reg_sum[0] / denom);
        out[0] = contrastive + reg;
    }
}

// ---------------------------------------------------------------------------
extern "C" void kernel_launch(void* const* d_in, const int* in_sizes, int n_in,
                              void* d_out, int out_size, void* d_ws, size_t ws_size,
                              hipStream_t stream) {
    const float* tf = (const float*)d_in[0];   // (B, NT, D) fp32
    const float* vf = (const float*)d_in[1];   // (B, NV, D) fp32
    const int* mask = (const int*)d_in[2];     // (B, NT) int32
    float* out = (float*)d_out;                // scalar fp32

    char* ws = (char*)d_ws;
    size_t tn_bytes = (size_t)BB * NT * DD;              // 4 MB fp8
    size_t vn_bytes = (size_t)BB * NV * DD;              // 8 MB fp8
    size_t cs_bytes = (size_t)BB * BB * sizeof(float);   // 16 KB

    uchar* tn = (uchar*)ws;
    uchar* vn = (uchar*)(ws + tn_bytes);
    float* clip_sims = (float*)(ws + tn_bytes + vn_bytes);
    float* reg_sum = (float*)(ws + tn_bytes + vn_bytes + cs_bytes);

    k_normalize<<<(BB * NT + BB * NV) / 4, 256, 0, stream>>>(tf, vf, tn, vn, reg_sum);
    // 1024 blocks: 64 i x 16 j-groups (4 visual batches per block).
    k_gemm<<<dim3(BB, BB / 4), 512, 0, stream>>>(tn, vn, mask, clip_sims, reg_sum);
    k_loss<<<1, 256, 0, stream>>>(clip_sims, reg_sum, out);
}

// Round 12
// 293.451 us; speedup vs baseline: 1.7930x; 1.7930x over previous
//
#include <hip/hip_runtime.h>
#include <hip/hip_bf16.h>

// Problem constants
#define BB 64     // batch
#define NT 128    // text tokens
#define NV 256    // visual tokens
#define DD 512    // feature dim (bytes per row in fp8)
#define BKB 128   // K-chunk in bytes: one 16x16x128 f8f6f4 k-step
#define EPSF 1e-7f

typedef __attribute__((ext_vector_type(8))) int i32x8;
typedef __attribute__((ext_vector_type(4))) int i32x4;
typedef __attribute__((ext_vector_type(4))) float f32x4;

__device__ __forceinline__ void glds16(const uchar* g, uchar* l) {
    __builtin_amdgcn_global_load_lds(
        (const __attribute__((address_space(1))) unsigned int*)g,
        (__attribute__((address_space(3))) unsigned int*)l, 16, 0, 0);
}

// ---------------------------------------------------------------------------
// Kernel 1: L2-normalize rows, write fp8 e4m3 (OCP). Wave per row.
// Also zeroes reg_sum and the completion counter for this iteration.
// ---------------------------------------------------------------------------
__global__ __launch_bounds__(256) void k_normalize(
    const float* __restrict__ tf, const float* __restrict__ vf,
    uchar* __restrict__ tn, uchar* __restrict__ vn,
    float* __restrict__ reg_sum, unsigned* __restrict__ done) {
    if (blockIdx.x == 0 && threadIdx.x == 0) { *reg_sum = 0.0f; *done = 0u; }
    const int w = threadIdx.x >> 6, l = threadIdx.x & 63;
    const int row = blockIdx.x * 4 + w;
    const float* src;
    uchar* dst;
    if (row < BB * NT) {
        src = tf + (size_t)row * DD;
        dst = tn + (size_t)row * DD;
    } else {
        int r = row - BB * NT;
        src = vf + (size_t)r * DD;
        dst = vn + (size_t)r * DD;
    }
    float4 x0 = ((const float4*)src)[l * 2];
    float4 x1 = ((const float4*)src)[l * 2 + 1];
    float ss = x0.x * x0.x + x0.y * x0.y + x0.z * x0.z + x0.w * x0.w
             + x1.x * x1.x + x1.y * x1.y + x1.z * x1.z + x1.w * x1.w;
    #pragma unroll
    for (int off = 32; off; off >>= 1) ss += __shfl_xor(ss, off, 64);
    float scale = 1.0f / fmaxf(sqrtf(ss), 1e-12f);
    int p0 = __builtin_amdgcn_cvt_pk_fp8_f32(x0.x * scale, x0.y * scale, 0, 0);
    p0 = __builtin_amdgcn_cvt_pk_fp8_f32(x0.z * scale, x0.w * scale, p0, 1);
    int p1 = __builtin_amdgcn_cvt_pk_fp8_f32(x1.x * scale, x1.y * scale, 0, 0);
    p1 = __builtin_amdgcn_cvt_pk_fp8_f32(x1.z * scale, x1.w * scale, p1, 1);
    ((uint2*)dst)[l] = make_uint2((unsigned)p0, (unsigned)p1);
}

// ---------------------------------------------------------------------------
// Kernel 2: EXACT R8 structure (the only spill-free shape: 512 thr, 8 waves
// 2x4, acc[4][4], T+V LDS DMA double-buffer, 2-deep counted-vmcnt schedule,
// VGPR=128, k_gemm ~150.8us) + FUSED FINAL LOSS: after the per-block
// epilogue, __threadfence + device-scope atomic counter; the last of the
// 4096 blocks computes the InfoNCE loss in-kernel, with its scratch LDS
// aliased onto the then-dead sV0/sV1 (zero LDS growth). Eliminates the
// k_loss launch (~10us) and its single-block serial latency.
// Structural note (rounds 2-11 mapping): this kernel is register-wall
// pinned -- 192 unified regs/wave => 2 waves/SIMD, 1 block/CU; deeper
// schedules are null (R8==R4), bigger tiles / more waves / in-loop flush
// all spill ~600B/thread. ~150us is this structure's K-loop ceiling.
// ---------------------------------------------------------------------------
__global__ __launch_bounds__(512, 2) void k_gemm(
    const uchar* __restrict__ tn, const uchar* __restrict__ vn,
    const int* __restrict__ mask,
    float* __restrict__ clip_sims, float* __restrict__ reg_sum,
    unsigned* __restrict__ done, float* __restrict__ out) {
    __shared__ uchar sT0[NT * BKB];   // 16 KB
    __shared__ uchar sT1[NT * BKB];   // 16 KB
    __shared__ uchar sV0[NV * BKB];   // 32 KB
    __shared__ uchar sV1[NV * BKB];   // 32 KB
    __shared__ float maxbuf[NT][4];   // row-max partials per wave col-group
    __shared__ float redw[8];
    __shared__ float c0[2], c1[2];
    __shared__ unsigned sflag;

    const int i = blockIdx.x, j = blockIdx.y;
    const int tid = threadIdx.x;
    const int l = tid & 63, w = tid >> 6;
    const int wr = w >> 2, wc = w & 3;      // wave row-group (0..1), col-group (0..3)
    const int m15 = l & 15, q = l >> 4;

    const uchar* tbase = tn + (size_t)i * NT * DD;
    const uchar* vbase = vn + (size_t)j * NV * DD;

    // Staging: 16B unit f -> row r = f>>3, phys granule p = f&7 holds
    // logical granule g = (p - r) & 7.  src = r*DD + kk + g*16.
    int t_off[2], v_off[4];
    #pragma unroll
    for (int s = 0; s < 2; ++s) {
        int f = s * 512 + tid;
        int r = f >> 3, p = f & 7, g = (p - r) & 7;
        t_off[s] = r * DD + g * 16;
    }
    #pragma unroll
    for (int s = 0; s < 4; ++s) {
        int f = s * 512 + tid;
        int r = f >> 3, p = f & 7, g = (p - r) & 7;
        v_off[s] = r * DD + g * 16;
    }

    // Fragment read addresses: lane holds k = q*32..q*32+31 of its row,
    // logical granules 2q, 2q+1 -> phys (2q+row)&7, (2q+1+row)&7.
    int a_b0[4], a_b1[4], b_b0[4], b_b1[4];
    #pragma unroll
    for (int rt = 0; rt < 4; ++rt) {
        int row = wr * 64 + rt * 16 + m15;
        a_b0[rt] = row * BKB + (((2 * q + row) & 7) * 16);
        a_b1[rt] = row * BKB + (((2 * q + 1 + row) & 7) * 16);
    }
    #pragma unroll
    for (int ct = 0; ct < 4; ++ct) {
        int row = wc * 64 + ct * 16 + m15;
        b_b0[ct] = row * BKB + (((2 * q + row) & 7) * 16);
        b_b1[ct] = row * BKB + (((2 * q + 1 + row) & 7) * 16);
    }

    f32x4 acc[4][4];
    #pragma unroll
    for (int rt = 0; rt < 4; ++rt)
        #pragma unroll
        for (int ct = 0; ct < 4; ++ct) acc[rt][ct] = (f32x4){0.f, 0.f, 0.f, 0.f};

    auto stage = [&](uchar* dT, uchar* dV, int kk) {
        #pragma unroll
        for (int s = 0; s < 2; ++s)
            glds16(tbase + t_off[s] + kk, dT + (s * 512 + tid) * 16);
        #pragma unroll
        for (int s = 0; s < 4; ++s)
            glds16(vbase + v_off[s] + kk, dV + (s * 512 + tid) * 16);
    };
    auto compute = [&](const uchar* bT, const uchar* bV) {
        i32x8 bf[4];
        #pragma unroll
        for (int ct = 0; ct < 4; ++ct) {
            i32x4 lo = *(const i32x4*)(bV + b_b0[ct]);
            i32x4 hi = *(const i32x4*)(bV + b_b1[ct]);
            bf[ct] = (i32x8){lo.x, lo.y, lo.z, lo.w, hi.x, hi.y, hi.z, hi.w};
        }
        #pragma unroll
        for (int rt = 0; rt < 4; ++rt) {
            i32x4 lo = *(const i32x4*)(bT + a_b0[rt]);
            i32x4 hi = *(const i32x4*)(bT + a_b1[rt]);
            i32x8 a = (i32x8){lo.x, lo.y, lo.z, lo.w, hi.x, hi.y, hi.z, hi.w};
            #pragma unroll
            for (int ct = 0; ct < 4; ++ct)
                acc[rt][ct] = __builtin_amdgcn_mfma_scale_f32_16x16x128_f8f6f4(
                    a, bf[ct], acc[rt][ct],
                    0 /*A fmt=fp8*/, 0 /*B fmt=fp8*/,
                    0, 127 /*scaleA=1.0*/, 0, 127 /*scaleB=1.0*/);
        }
    };

    // --- 2-deep pipelined schedule with counted vmcnt (R8-verified) -------
    stage(sT0, sV0, 0);          // tile 0 -> 6 outstanding
    stage(sT1, sV1, 1 * BKB);    // tile 1 -> 12 outstanding

    // ks = 0
    asm volatile("s_waitcnt vmcnt(6)" ::: "memory");   // tile 0 landed
    __builtin_amdgcn_s_barrier();
    asm volatile("" ::: "memory");
    compute(sT0, sV0);
    asm volatile("" ::: "memory");
    __builtin_amdgcn_s_barrier();                      // all done reading buf0
    stage(sT0, sV0, 2 * BKB);    // tile 2 -> 12 outstanding

    // ks = 1
    asm volatile("s_waitcnt vmcnt(6)" ::: "memory");   // tile 1 landed
    __builtin_amdgcn_s_barrier();
    asm volatile("" ::: "memory");
    compute(sT1, sV1);
    asm volatile("" ::: "memory");
    __builtin_amdgcn_s_barrier();                      // all done reading buf1
    stage(sT1, sV1, 3 * BKB);    // tile 3 -> 12 outstanding

    // ks = 2
    asm volatile("s_waitcnt vmcnt(6)" ::: "memory");   // tile 2 landed
    __builtin_amdgcn_s_barrier();
    asm volatile("" ::: "memory");
    compute(sT0, sV0);
    asm volatile("" ::: "memory");
    __builtin_amdgcn_s_barrier();

    // ks = 3
    asm volatile("s_waitcnt vmcnt(0)" ::: "memory");   // tile 3 landed
    __builtin_amdgcn_s_barrier();
    asm volatile("" ::: "memory");
    compute(sT1, sV1);

    // Epilogue 1: reg partial = sum of min(s,0)^2 over this lane's 64 values.
    float rp = 0.0f;
    #pragma unroll
    for (int rt = 0; rt < 4; ++rt)
        #pragma unroll
        for (int ct = 0; ct < 4; ++ct)
            #pragma unroll
            for (int r = 0; r < 4; ++r) {
                float m = fminf(acc[rt][ct][r], 0.0f);
                rp = fmaf(m, m, rp);
            }

    // Epilogue 2: row max. C/D layout: col = lane&15, row = q*4 + reg.
    #pragma unroll
    for (int rt = 0; rt < 4; ++rt)
        #pragma unroll
        for (int r = 0; r < 4; ++r) {
            float m = acc[rt][0][r];
            #pragma unroll
            for (int ct = 1; ct < 4; ++ct) m = fmaxf(m, acc[rt][ct][r]);
            #pragma unroll
            for (int msk = 1; msk < 16; msk <<= 1)
                m = fmaxf(m, __shfl_xor(m, msk, 64));
            if (m15 == 0)
                maxbuf[wr * 64 + rt * 16 + q * 4 + r][wc] = m;
        }

    #pragma unroll
    for (int off = 32; off; off >>= 1) rp += __shfl_down(rp, off, 64);
    if (l == 0) redw[w] = rp;
    __syncthreads();

    // Fused clip: masked mean of row maxes over the 128 text tokens.
    if (tid < NT) {
        float rm = fmaxf(fmaxf(maxbuf[tid][0], maxbuf[tid][1]),
                         fmaxf(maxbuf[tid][2], maxbuf[tid][3]));
        float mf = (float)mask[i * NT + tid];
        float v = rm * mf;
        #pragma unroll
        for (int off = 32; off; off >>= 1) {
            v += __shfl_down(v, off, 64);
            mf += __shfl_down(mf, off, 64);
        }
        if (l == 0) { c0[w] = v; c1[w] = mf; }
    }
    __syncthreads();
    if (tid == 0) {
        clip_sims[i * BB + j] = (c0[0] + c0[1]) / fmaxf(c1[0] + c1[1], EPSF);
        float s = 0.0f;
        #pragma unroll
        for (int x = 0; x < 8; ++x) s += redw[x];
        atomicAdd(reg_sum, s);
        // Publish this block's writes, then take a completion ticket.
        __threadfence();
        unsigned old = atomicAdd(done, 1u);
        sflag = (old == (unsigned)(BB * BB - 1)) ? 1u : 0u;
    }
    __syncthreads();

    // ---- Last block only: compute the final scalar loss in-kernel --------
    if (sflag) {
        // All producers fenced before their counter increment; we hold the
        // final ticket, so clip_sims/reg_sum are device-visible. Scratch LDS
        // aliased onto the dead V buffers (no LDS growth, no reg pressure
        // in the hot path -- cold uniformly-branched tail).
        float* sc = (float*)sV0;            // 64*65 floats = 16.6 KB < 32 KB
        float* lrow = (float*)sV1;          // 64 floats
        float* lcol = lrow + BB;            // 64 floats
        volatile const float* cs = (volatile const float*)clip_sims;
        for (int idx = tid; idx < BB * BB; idx += 512)
            sc[(idx >> 6) * (BB + 1) + (idx & 63)] = cs[idx];
        __syncthreads();
        if (tid < BB) {
            int r = tid;
            float m = sc[r * (BB + 1)];
            #pragma unroll
            for (int c = 1; c < BB; ++c) m = fmaxf(m, sc[r * (BB + 1) + c]);
            float s = 0.0f;
            #pragma unroll
            for (int c = 0; c < BB; ++c) s += expf(sc[r * (BB + 1) + c] - m);
            lrow[r] = m + logf(s) - sc[r * (BB + 1) + r];
        } else if (tid < 2 * BB) {
            int c = tid - BB;
            float m = sc[c];
            #pragma unroll
            for (int r = 1; r < BB; ++r) m = fmaxf(m, sc[r * (BB + 1) + c]);
            float s = 0.0f;
            #pragma unroll
            for (int r = 0; r < BB; ++r) s += expf(sc[r * (BB + 1) + c] - m);
            lcol[c] = m + logf(s) - sc[c * (BB + 1) + c];
        }
        __syncthreads();
        if (tid == 0) {
            float tot = 0.0f;
            for (int r = 0; r < BB; ++r) tot += lrow[r] + lcol[r];
            float contrastive = tot / (2.0f * BB);
            double denom = (double)BB * BB * NT * NV;  // 134217728
            volatile const float* rs = (volatile const float*)reg_sum;
            float reg = 0.15f * (float)((double)rs[0] / denom);
            out[0] = contrastive + reg;
        }
    }
}

// ---------------------------------------------------------------------------
extern "C" void kernel_launch(void* const* d_in, const int* in_sizes, int n_in,
                              void* d_out, int out_size, void* d_ws, size_t ws_size,
                              hipStream_t stream) {
    const float* tf = (const float*)d_in[0];   // (B, NT, D) fp32
    const float* vf = (const float*)d_in[1];   // (B, NV, D) fp32
    const int* mask = (const int*)d_in[2];     // (B, NT) int32
    float* out = (float*)d_out;                // scalar fp32

    char* ws = (char*)d_ws;
    size_t tn_bytes = (size_t)BB * NT * DD;              // 4 MB fp8
    size_t vn_bytes = (size_t)BB * NV * DD;              // 8 MB fp8
    size_t cs_bytes = (size_t)BB * BB * sizeof(float);   // 16 KB

    uchar* tn = (uchar*)ws;
    uchar* vn = (uchar*)(ws + tn_bytes);
    float* clip_sims = (float*)(ws + tn_bytes + vn_bytes);
    float* reg_sum = (float*)(ws + tn_bytes + vn_bytes + cs_bytes);
    unsigned* done = (unsigned*)(ws + tn_bytes + vn_bytes + cs_bytes + sizeof(float));

    k_normalize<<<(BB * NT + BB * NV) / 4, 256, 0, stream>>>(tf, vf, tn, vn,
                                                             reg_sum, done);
    k_gemm<<<dim3(BB, BB), 512, 0, stream>>>(tn, vn, mask, clip_sims,
                                             reg_sum, done, out);
}

// Round 13
// 230.894 us; speedup vs baseline: 2.2788x; 1.2709x over previous
//
#include <hip/hip_runtime.h>
#include <hip/hip_bf16.h>

// Problem constants
#define BB 64     // batch
#define NT 128    // text tokens
#define NV 256    // visual tokens
#define DD 512    // feature dim (bytes per row in fp8)
#define BKB 128   // K-chunk in bytes: one 16x16x128 f8f6f4 k-step
#define EPSF 1e-7f

typedef __attribute__((ext_vector_type(8))) int i32x8;
typedef __attribute__((ext_vector_type(4))) int i32x4;
typedef __attribute__((ext_vector_type(4))) float f32x4;

__device__ __forceinline__ void glds16(const uchar* g, uchar* l) {
    __builtin_amdgcn_global_load_lds(
        (const __attribute__((address_space(1))) unsigned int*)g,
        (__attribute__((address_space(3))) unsigned int*)l, 16, 0, 0);
}

// ---------------------------------------------------------------------------
// Kernel 1: L2-normalize rows, write fp8 e4m3 (OCP). Wave per row.
// ---------------------------------------------------------------------------
__global__ __launch_bounds__(256) void k_normalize(
    const float* __restrict__ tf, const float* __restrict__ vf,
    uchar* __restrict__ tn, uchar* __restrict__ vn,
    float* __restrict__ reg_sum) {
    if (blockIdx.x == 0 && threadIdx.x == 0) *reg_sum = 0.0f;
    const int w = threadIdx.x >> 6, l = threadIdx.x & 63;
    const int row = blockIdx.x * 4 + w;
    const float* src;
    uchar* dst;
    if (row < BB * NT) {
        src = tf + (size_t)row * DD;
        dst = tn + (size_t)row * DD;
    } else {
        int r = row - BB * NT;
        src = vf + (size_t)r * DD;
        dst = vn + (size_t)r * DD;
    }
    float4 x0 = ((const float4*)src)[l * 2];
    float4 x1 = ((const float4*)src)[l * 2 + 1];
    float ss = x0.x * x0.x + x0.y * x0.y + x0.z * x0.z + x0.w * x0.w
             + x1.x * x1.x + x1.y * x1.y + x1.z * x1.z + x1.w * x1.w;
    #pragma unroll
    for (int off = 32; off; off >>= 1) ss += __shfl_xor(ss, off, 64);
    float scale = 1.0f / fmaxf(sqrtf(ss), 1e-12f);
    int p0 = __builtin_amdgcn_cvt_pk_fp8_f32(x0.x * scale, x0.y * scale, 0, 0);
    p0 = __builtin_amdgcn_cvt_pk_fp8_f32(x0.z * scale, x0.w * scale, p0, 1);
    int p1 = __builtin_amdgcn_cvt_pk_fp8_f32(x1.x * scale, x1.y * scale, 0, 0);
    p1 = __builtin_amdgcn_cvt_pk_fp8_f32(x1.z * scale, x1.w * scale, p1, 1);
    ((uint2*)dst)[l] = make_uint2((unsigned)p0, (unsigned)p1);
}

// ---------------------------------------------------------------------------
// Kernel 2: the measured-optimal structure (R8, 230.35us total, k_gemm
// ~150.8us, absmax 0.0). 128x256 tile per (i,j) pair, T+V LDS DMA double
// buffer with rotation swizzle, acc[4][4] (VGPR=128 -- the ONLY spill-free
// register shape, verified across 12 rounds), 2-deep prefetch with counted
// vmcnt, post-loop epilogue.
// Session map (rounds 2-12): this kernel is register-wall pinned. 192
// unified regs/wave => 2 waves/SIMD => 1 block/CU. Measured nulls/failures:
// deeper schedules (R8==R4), bigger tiles (spill), more waves via bounds
// (ignored/spill), 4-wave blocks (spill), multi-j amortization (spill),
// direct-global operands (latency, -47%), fused loss tail (+19B/thr spill,
// -30%). ~150us k_gemm is this structure's ceiling; MfmaUtil 18% / HBM 4%
// means the residual is latency at 2 waves/SIMD, not a saturated pipe.
// ---------------------------------------------------------------------------
__global__ __launch_bounds__(512, 2) void k_gemm(
    const uchar* __restrict__ tn, const uchar* __restrict__ vn,
    const int* __restrict__ mask,
    float* __restrict__ clip_sims, float* __restrict__ reg_sum) {
    __shared__ uchar sT0[NT * BKB];   // 16 KB
    __shared__ uchar sT1[NT * BKB];   // 16 KB
    __shared__ uchar sV0[NV * BKB];   // 32 KB
    __shared__ uchar sV1[NV * BKB];   // 32 KB
    __shared__ float maxbuf[NT][4];   // row-max partials per wave col-group
    __shared__ float redw[8];
    __shared__ float c0[2], c1[2];

    const int i = blockIdx.x, j = blockIdx.y;
    const int tid = threadIdx.x;
    const int l = tid & 63, w = tid >> 6;
    const int wr = w >> 2, wc = w & 3;      // wave row-group (0..1), col-group (0..3)
    const int m15 = l & 15, q = l >> 4;

    const uchar* tbase = tn + (size_t)i * NT * DD;
    const uchar* vbase = vn + (size_t)j * NV * DD;

    // Staging: 16B unit f -> row r = f>>3, phys granule p = f&7 holds
    // logical granule g = (p - r) & 7.  src = r*DD + kk + g*16.
    int t_off[2], v_off[4];
    #pragma unroll
    for (int s = 0; s < 2; ++s) {
        int f = s * 512 + tid;
        int r = f >> 3, p = f & 7, g = (p - r) & 7;
        t_off[s] = r * DD + g * 16;
    }
    #pragma unroll
    for (int s = 0; s < 4; ++s) {
        int f = s * 512 + tid;
        int r = f >> 3, p = f & 7, g = (p - r) & 7;
        v_off[s] = r * DD + g * 16;
    }

    // Fragment read addresses: lane holds k = q*32..q*32+31 of its row,
    // logical granules 2q, 2q+1 -> phys (2q+row)&7, (2q+1+row)&7.
    int a_b0[4], a_b1[4], b_b0[4], b_b1[4];
    #pragma unroll
    for (int rt = 0; rt < 4; ++rt) {
        int row = wr * 64 + rt * 16 + m15;
        a_b0[rt] = row * BKB + (((2 * q + row) & 7) * 16);
        a_b1[rt] = row * BKB + (((2 * q + 1 + row) & 7) * 16);
    }
    #pragma unroll
    for (int ct = 0; ct < 4; ++ct) {
        int row = wc * 64 + ct * 16 + m15;
        b_b0[ct] = row * BKB + (((2 * q + row) & 7) * 16);
        b_b1[ct] = row * BKB + (((2 * q + 1 + row) & 7) * 16);
    }

    f32x4 acc[4][4];
    #pragma unroll
    for (int rt = 0; rt < 4; ++rt)
        #pragma unroll
        for (int ct = 0; ct < 4; ++ct) acc[rt][ct] = (f32x4){0.f, 0.f, 0.f, 0.f};

    auto stage = [&](uchar* dT, uchar* dV, int kk) {
        #pragma unroll
        for (int s = 0; s < 2; ++s)
            glds16(tbase + t_off[s] + kk, dT + (s * 512 + tid) * 16);
        #pragma unroll
        for (int s = 0; s < 4; ++s)
            glds16(vbase + v_off[s] + kk, dV + (s * 512 + tid) * 16);
    };
    auto compute = [&](const uchar* bT, const uchar* bV) {
        i32x8 bf[4];
        #pragma unroll
        for (int ct = 0; ct < 4; ++ct) {
            i32x4 lo = *(const i32x4*)(bV + b_b0[ct]);
            i32x4 hi = *(const i32x4*)(bV + b_b1[ct]);
            bf[ct] = (i32x8){lo.x, lo.y, lo.z, lo.w, hi.x, hi.y, hi.z, hi.w};
        }
        #pragma unroll
        for (int rt = 0; rt < 4; ++rt) {
            i32x4 lo = *(const i32x4*)(bT + a_b0[rt]);
            i32x4 hi = *(const i32x4*)(bT + a_b1[rt]);
            i32x8 a = (i32x8){lo.x, lo.y, lo.z, lo.w, hi.x, hi.y, hi.z, hi.w};
            #pragma unroll
            for (int ct = 0; ct < 4; ++ct)
                acc[rt][ct] = __builtin_amdgcn_mfma_scale_f32_16x16x128_f8f6f4(
                    a, bf[ct], acc[rt][ct],
                    0 /*A fmt=fp8*/, 0 /*B fmt=fp8*/,
                    0, 127 /*scaleA=1.0*/, 0, 127 /*scaleB=1.0*/);
        }
    };

    // --- 2-deep pipelined schedule with counted vmcnt ---------------------
    // Outstanding DMA per wave is always {oldest tile: 6, newest tile: 6}.
    stage(sT0, sV0, 0);          // tile 0 -> 6 outstanding
    stage(sT1, sV1, 1 * BKB);    // tile 1 -> 12 outstanding

    // ks = 0
    asm volatile("s_waitcnt vmcnt(6)" ::: "memory");   // tile 0 landed
    __builtin_amdgcn_s_barrier();
    asm volatile("" ::: "memory");
    compute(sT0, sV0);
    asm volatile("" ::: "memory");
    __builtin_amdgcn_s_barrier();                      // all done reading buf0
    stage(sT0, sV0, 2 * BKB);    // tile 2 -> 12 outstanding

    // ks = 1
    asm volatile("s_waitcnt vmcnt(6)" ::: "memory");   // tile 1 landed
    __builtin_amdgcn_s_barrier();
    asm volatile("" ::: "memory");
    compute(sT1, sV1);
    asm volatile("" ::: "memory");
    __builtin_amdgcn_s_barrier();                      // all done reading buf1
    stage(sT1, sV1, 3 * BKB);    // tile 3 -> 12 outstanding

    // ks = 2
    asm volatile("s_waitcnt vmcnt(6)" ::: "memory");   // tile 2 landed
    __builtin_amdgcn_s_barrier();
    asm volatile("" ::: "memory");
    compute(sT0, sV0);
    asm volatile("" ::: "memory");
    __builtin_amdgcn_s_barrier();

    // ks = 3
    asm volatile("s_waitcnt vmcnt(0)" ::: "memory");   // tile 3 landed
    __builtin_amdgcn_s_barrier();
    asm volatile("" ::: "memory");
    compute(sT1, sV1);

    // Epilogue 1: reg partial = sum of min(s,0)^2 over this lane's 64 values.
    float rp = 0.0f;
    #pragma unroll
    for (int rt = 0; rt < 4; ++rt)
        #pragma unroll
        for (int ct = 0; ct < 4; ++ct)
            #pragma unroll
            for (int r = 0; r < 4; ++r) {
                float m = fminf(acc[rt][ct][r], 0.0f);
                rp = fmaf(m, m, rp);
            }

    // Epilogue 2: row max. C/D layout: col = lane&15, row = q*4 + reg.
    #pragma unroll
    for (int rt = 0; rt < 4; ++rt)
        #pragma unroll
        for (int r = 0; r < 4; ++r) {
            float m = acc[rt][0][r];
            #pragma unroll
            for (int ct = 1; ct < 4; ++ct) m = fmaxf(m, acc[rt][ct][r]);
            #pragma unroll
            for (int msk = 1; msk < 16; msk <<= 1)
                m = fmaxf(m, __shfl_xor(m, msk, 64));
            if (m15 == 0)
                maxbuf[wr * 64 + rt * 16 + q * 4 + r][wc] = m;
        }

    #pragma unroll
    for (int off = 32; off; off >>= 1) rp += __shfl_down(rp, off, 64);
    if (l == 0) redw[w] = rp;
    __syncthreads();

    // Fused clip: masked mean of row maxes over the 128 text tokens.
    if (tid < NT) {
        float rm = fmaxf(fmaxf(maxbuf[tid][0], maxbuf[tid][1]),
                         fmaxf(maxbuf[tid][2], maxbuf[tid][3]));
        float mf = (float)mask[i * NT + tid];
        float v = rm * mf;
        #pragma unroll
        for (int off = 32; off; off >>= 1) {
            v += __shfl_down(v, off, 64);
            mf += __shfl_down(mf, off, 64);
        }
        if (l == 0) { c0[w] = v; c1[w] = mf; }
    }
    __syncthreads();
    if (tid == 0) {
        clip_sims[i * BB + j] = (c0[0] + c0[1]) / fmaxf(c1[0] + c1[1], EPSF);
        float s = 0.0f;
        #pragma unroll
        for (int x = 0; x < 8; ++x) s += redw[x];
        atomicAdd(reg_sum, s);
    }
}

// ---------------------------------------------------------------------------
// Kernel 3: final scalar loss. Single block, 256 threads.
// ---------------------------------------------------------------------------
__global__ __launch_bounds__(256) void k_loss(
    const float* __restrict__ clip_sims, const float* __restrict__ reg_sum,
    float* __restrict__ out) {
    __shared__ float sc[BB][BB + 1];
    __shared__ float lrow[BB], lcol[BB];
    int tid = threadIdx.x;
    for (int idx = tid; idx < BB * BB; idx += 256)
        sc[idx / BB][idx % BB] = clip_sims[idx];
    __syncthreads();
    if (tid < BB) {
        int i = tid;
        float m = sc[i][0];
        #pragma unroll
        for (int j = 1; j < BB; ++j) m = fmaxf(m, sc[i][j]);
        float s = 0.0f;
        #pragma unroll
        for (int j = 0; j < BB; ++j) s += expf(sc[i][j] - m);
        lrow[i] = m + logf(s) - sc[i][i];
    } else if (tid < 2 * BB) {
        int i = tid - BB;
        float m = sc[0][i];
        #pragma unroll
        for (int j = 1; j < BB; ++j) m = fmaxf(m, sc[j][i]);
        float s = 0.0f;
        #pragma unroll
        for (int j = 0; j < BB; ++j) s += expf(sc[j][i] - m);
        lcol[i] = m + logf(s) - sc[i][i];
    }
    __syncthreads();
    if (tid == 0) {
        float tot = 0.0f;
        for (int i = 0; i < BB; ++i) tot += lrow[i] + lcol[i];
        float contrastive = tot / (2.0f * BB);
        double denom = (double)BB * BB * NT * NV;  // 134217728
        float reg = 0.15f * (float)((double)reg_sum[0] / denom);
        out[0] = contrastive + reg;
    }
}

// ---------------------------------------------------------------------------
extern "C" void kernel_launch(void* const* d_in, const int* in_sizes, int n_in,
                              void* d_out, int out_size, void* d_ws, size_t ws_size,
                              hipStream_t stream) {
    const float* tf = (const float*)d_in[0];   // (B, NT, D) fp32
    const float* vf = (const float*)d_in[1];   // (B, NV, D) fp32
    const int* mask = (const int*)d_in[2];     // (B, NT) int32
    float* out = (float*)d_out;                // scalar fp32

    char* ws = (char*)d_ws;
    size_t tn_bytes = (size_t)BB * NT * DD;              // 4 MB fp8
    size_t vn_bytes = (size_t)BB * NV * DD;              // 8 MB fp8
    size_t cs_bytes = (size_t)BB * BB * sizeof(float);   // 16 KB

    uchar* tn = (uchar*)ws;
    uchar* vn = (uchar*)(ws + tn_bytes);
    float* clip_sims = (float*)(ws + tn_bytes + vn_bytes);
    float* reg_sum = (float*)(ws + tn_bytes + vn_bytes + cs_bytes);

    k_normalize<<<(BB * NT + BB * NV) / 4, 256, 0, stream>>>(tf, vf, tn, vn, reg_sum);
    k_gemm<<<dim3(BB, BB), 512, 0, stream>>>(tn, vn, mask, clip_sims, reg_sum);
    k_loss<<<1, 256, 0, stream>>>(clip_sims, reg_sum, out);
}